// Round 5
// baseline (221.203 us; speedup 1.0000x reference)
//
#include <hip/hip_runtime.h>
#include <math.h>

#define D_IN 768
#define E_DIM 256
#define NB 32
#define NP 192
#define NA 30

typedef __attribute__((ext_vector_type(8))) __bf16 bf16x8;
typedef __attribute__((ext_vector_type(4))) float f32x4;

__device__ __forceinline__ bf16x8 cvt8(float4 a, float4 b) {
    bf16x8 v;
    v[0]=(__bf16)a.x; v[1]=(__bf16)a.y; v[2]=(__bf16)a.z; v[3]=(__bf16)a.w;
    v[4]=(__bf16)b.x; v[5]=(__bf16)b.y; v[6]=(__bf16)b.z; v[7]=(__bf16)b.w;
    return v;
}

// ---------------------------------------------------------------------------
// GEMM kernel: Y[7232][256] = rows(X) @ W^T (fp32 out, no bias).
// Row space (16-row groups r16 = 0..451):
//   [0,384)   patch: v = r16/12, sub = r16%12  -> vf[v*193 + 1 + sub*16 + i]
//   [384,448) att:   t = (r16-384)/2, half=&1  -> tf[t*31 + 1 + half*16+i] (i>=30 dup 0)
//   448,449   vis CLS: vf[(r16-448)*16+i)*193]
//   450,451   txt CLS: tf[(r16-450)*16+i)*31]
// grid = 452*4 blocks; block = (r16, cg); wave w computes tile (r16, cg*4+w):
// 16 rows x 16 cols, full K=768. One wave = one tile; 7 blocks/CU.
// ---------------------------------------------------------------------------
__global__ __launch_bounds__(256) void gemm_kernel(
    const float* __restrict__ vf, const float* __restrict__ tf,
    const float* __restrict__ Wv, const float* __restrict__ Wt,
    const float* __restrict__ Wp, const float* __restrict__ Wa,
    float* __restrict__ Yws)
{
    const int bid = blockIdx.x;
    const int r16 = bid >> 2, cg = bid & 3;
    const int tid = threadIdx.x;
    const int w = tid >> 6, l = tid & 63, q = l >> 4, n15 = l & 15;

    const float* arow;
    const float* W;
    if (r16 < 384) {
        const int v = r16 / 12, sub = r16 - 12 * v;
        arow = vf + (size_t)(v * 193 + 1 + sub * 16 + n15) * D_IN;
        W = Wp;
    } else if (r16 < 448) {
        const int u = r16 - 384, t = u >> 1, half = u & 1;
        const int ridx = half * 16 + n15;
        const int r = (ridx < NA) ? ridx : 0;
        arow = tf + (size_t)(t * 31 + 1 + r) * D_IN;
        W = Wa;
    } else if (r16 < 450) {
        arow = vf + (size_t)((r16 - 448) * 16 + n15) * 193 * D_IN;
        W = Wv;
    } else {
        arow = tf + (size_t)((r16 - 450) * 16 + n15) * 31 * D_IN;
        W = Wt;
    }
    const float* wrow = W + (size_t)(cg * 64 + w * 16 + n15) * D_IN;

    f32x4 acc = {0.f, 0.f, 0.f, 0.f};
    const int kq8 = q * 8;
    #pragma unroll 4
    for (int kt = 0; kt < 24; ++kt) {
        const int k0 = kt * 32 + kq8;
        float4 a0 = *(const float4*)&arow[k0];
        float4 a1 = *(const float4*)&arow[k0 + 4];
        float4 b0 = *(const float4*)&wrow[k0];
        float4 b1 = *(const float4*)&wrow[k0 + 4];
        bf16x8 af = cvt8(a0, a1);
        bf16x8 bf_ = cvt8(b0, b1);
        acc = __builtin_amdgcn_mfma_f32_16x16x32_bf16(af, bf_, acc, 0, 0, 0);
    }

    // C-layout: col = n15, row = q*4 + r
    const int col = cg * 64 + w * 16 + n15;
    #pragma unroll
    for (int r = 0; r < 4; ++r)
        Yws[(size_t)(r16 * 16 + q * 4 + r) * E_DIM + col] = acc[r];
}

// ---------------------------------------------------------------------------
// Pack kernel: 226 blocks. Loads 32 Y rows (+bias) to LDS, then norms/means/
// embeds and bf16 fragment packs for the pair kernel:
//   pn_frag[v][c] : l2norm(patch) A-row-frag  [mt2][koct8][lane64][8]
//   pB_frag[v][c] : raw patch B-frag (k=p)    [nt16][lane64][8]
//   an_frag[t]    : l2norm(att) row-frag      [at2][koct8][lane64][8]
//   attT_frag[t]  : raw att B-frag (k=a)      [nt16][lane64][8]
// ---------------------------------------------------------------------------
__global__ __launch_bounds__(256) void pack_kernel(
    const float* __restrict__ Yws,
    const float* __restrict__ bv, const float* __restrict__ bt,
    const float* __restrict__ bp, const float* __restrict__ ba,
    const int* __restrict__ att_nums,
    float* __restrict__ out_vis, float* __restrict__ out_txt,
    float* __restrict__ out_pm, float* __restrict__ out_am,
    __bf16* __restrict__ pn_frag, __bf16* __restrict__ pB_frag,
    __bf16* __restrict__ an_frag, __bf16* __restrict__ attT_frag)
{
    __shared__ float LDSf[32 * 260];
    __shared__ float invn_s[32];

    const int bid = blockIdx.x;
    const int tid = threadIdx.x;

    int role, base;
    const float* bias;
    if (bid < 192)       { role = 0; base = 32 * bid;              bias = bp; }
    else if (bid < 224)  { role = 1; base = 6144 + 32 * (bid-192); bias = ba; }
    else if (bid == 224) { role = 2; base = 7168;                  bias = bv; }
    else                 { role = 3; base = 7200;                  bias = bt; }

    // embeds: straight copy + bias
    if (role >= 2) {
        float* outp = (role == 2) ? out_vis : out_txt;
        const float b = bias[tid];
        #pragma unroll
        for (int i = 0; i < 32; ++i)
            outp[i * E_DIM + tid] = Yws[(size_t)(base + i) * E_DIM + tid] + b;
        return;
    }

    {
        const float b = bias[tid];
        #pragma unroll
        for (int i = 0; i < 32; ++i)
            LDSf[i * 260 + tid] = Yws[(size_t)(base + i) * E_DIM + tid] + b;
    }
    __syncthreads();

    if (role == 0) {
        const int v = bid / 6, c = bid - 6 * v;
        {
            const int row = tid >> 3, seg = tid & 7;
            const float* rr = &LDSf[row * 260 + seg * 32];
            float ssq = 0.f;
            #pragma unroll
            for (int j = 0; j < 32; ++j) ssq += rr[j] * rr[j];
            ssq += __shfl_xor(ssq, 1, 64);
            ssq += __shfl_xor(ssq, 2, 64);
            ssq += __shfl_xor(ssq, 4, 64);
            if (seg == 0) invn_s[row] = 1.f / fmaxf(sqrtf(ssq), 1e-12f);
        }
        {
            float s = 0.f;
            #pragma unroll
            for (int r = 0; r < 32; ++r) s += LDSf[r * 260 + tid];
            atomicAdd(&out_pm[v * E_DIM + tid], s * (1.f / 192.f));
        }
        __syncthreads();
        __bf16* dstn = pn_frag + (size_t)(v * 6 + c) * 8192;
        #pragma unroll
        for (int i = 0; i < 4; ++i) {
            const int slot = tid + 256 * i;
            const int mt = slot >> 9, koct = (slot >> 6) & 7, lane = slot & 63;
            const int prl = mt * 16 + (lane & 15);
            const int e0 = koct * 32 + (lane >> 4) * 8;
            const float inr = invn_s[prl];
            const float* src = &LDSf[prl * 260 + e0];
            bf16x8 vv;
            #pragma unroll
            for (int j = 0; j < 8; ++j) vv[j] = (__bf16)(src[j] * inr);
            *(bf16x8*)&dstn[slot * 8] = vv;
        }
        __bf16* dstb = pB_frag + (size_t)(v * 6 + c) * 8192;
        #pragma unroll
        for (int i = 0; i < 4; ++i) {
            const int slot = tid + 256 * i;
            const int nt = slot >> 6, lane = slot & 63;
            const int e = nt * 16 + (lane & 15);
            const int p0 = (lane >> 4) * 8;
            bf16x8 vv;
            #pragma unroll
            for (int j = 0; j < 8; ++j) vv[j] = (__bf16)LDSf[(p0 + j) * 260 + e];
            *(bf16x8*)&dstb[slot * 8] = vv;
        }
    } else {
        const int t = bid - 192;
        const int Av = att_nums[t];
        {
            const int row = tid >> 3, seg = tid & 7;
            const float* rr = &LDSf[row * 260 + seg * 32];
            float ssq = 0.f;
            #pragma unroll
            for (int j = 0; j < 32; ++j) ssq += rr[j] * rr[j];
            ssq += __shfl_xor(ssq, 1, 64);
            ssq += __shfl_xor(ssq, 2, 64);
            ssq += __shfl_xor(ssq, 4, 64);
            if (seg == 0) invn_s[row] = (row < NA) ? 1.f / fmaxf(sqrtf(ssq), 1e-12f) : 0.f;
        }
        {
            float s = 0.f;
            #pragma unroll
            for (int r = 0; r < NA; ++r) s += LDSf[r * 260 + tid];
            out_am[t * E_DIM + tid] = s / (float)Av;
        }
        __syncthreads();
        __bf16* dstn = an_frag + (size_t)t * 8192;
        #pragma unroll
        for (int i = 0; i < 4; ++i) {
            const int slot = tid + 256 * i;
            const int at = slot >> 9, koct = (slot >> 6) & 7, lane = slot & 63;
            const int a = at * 16 + (lane & 15);
            const int e0 = koct * 32 + (lane >> 4) * 8;
            const float inr = (a < NA) ? invn_s[a] : 0.f;
            const float* src = &LDSf[a * 260 + e0];
            bf16x8 vv;
            #pragma unroll
            for (int j = 0; j < 8; ++j) vv[j] = (__bf16)(src[j] * inr);
            *(bf16x8*)&dstn[slot * 8] = vv;
        }
        __bf16* dstb = attT_frag + (size_t)t * 8192;
        #pragma unroll
        for (int i = 0; i < 4; ++i) {
            const int slot = tid + 256 * i;
            const int nt = slot >> 6, lane = slot & 63;
            const int e = nt * 16 + (lane & 15);
            const int a0 = (lane >> 4) * 8;
            bf16x8 vv;
            #pragma unroll
            for (int j = 0; j < 8; ++j)
                vv[j] = (a0 + j < NA) ? (__bf16)LDSf[(a0 + j) * 260 + e] : (__bf16)0.f;
            *(bf16x8*)&dstb[slot * 8] = vv;
        }
    }
}

// ---------------------------------------------------------------------------
// MFMA pair kernel: one block per (v,t). All staging = contiguous 16B copies.
// ---------------------------------------------------------------------------
__global__ __launch_bounds__(256) void pair_mfma_kernel(
    const __bf16* __restrict__ pn_frag, const __bf16* __restrict__ pB_frag,
    const __bf16* __restrict__ an_frag, const __bf16* __restrict__ attT_frag,
    const int* __restrict__ att_nums, float* __restrict__ out_sim)
{
    __shared__ __align__(16) __bf16 an_s[8192];
    __shared__ __align__(16) __bf16 attT_s[8192];
    __shared__ __align__(16) __bf16 pn_s[8192];
    __shared__ __align__(16) __bf16 pB_s[8192];
    __shared__ __align__(16) __bf16 Xa_s[1024];
    __shared__ __align__(16) __bf16 XaT_s[1024];
    __shared__ float red_s[128];
    __shared__ float invn_s[32];
    __shared__ float wred_s[4];

    const int v = blockIdx.x, t = blockIdx.y;
    const int tid = threadIdx.x;
    const int w = tid >> 6, l = tid & 63, q = l >> 4, n15 = l & 15;
    const int Av = att_nums[t];

    {
        const __bf16* s1 = an_frag + (size_t)t * 8192;
        const __bf16* s2 = attT_frag + (size_t)t * 8192;
        #pragma unroll
        for (int i = 0; i < 4; ++i) {
            const int slot = tid + 256 * i;
            *(bf16x8*)&an_s[slot * 8]   = *(const bf16x8*)&s1[slot * 8];
            *(bf16x8*)&attT_s[slot * 8] = *(const bf16x8*)&s2[slot * 8];
        }
    }
    __syncthreads();

    bf16x8 ab[4];
    #pragma unroll
    for (int n = 0; n < 4; ++n)
        ab[n] = *(const bf16x8*)&attT_s[((w * 4 + n) * 64 + l) * 8];

    f32x4 apacc[2][4];
    #pragma unroll
    for (int m = 0; m < 2; ++m)
        #pragma unroll
        for (int n = 0; n < 4; ++n) { f32x4 z = {0.f,0.f,0.f,0.f}; apacc[m][n] = z; }
    float sa_acc[4] = {0.f, 0.f, 0.f, 0.f};

    for (int c = 0; c < 6; ++c) {
        __syncthreads();
        {
            const __bf16* sp1 = pn_frag + (size_t)(v * 6 + c) * 8192;
            const __bf16* sp2 = pB_frag + (size_t)(v * 6 + c) * 8192;
            #pragma unroll
            for (int i = 0; i < 4; ++i) {
                const int slot = tid + 256 * i;
                *(bf16x8*)&pn_s[slot * 8] = *(const bf16x8*)&sp1[slot * 8];
                *(bf16x8*)&pB_s[slot * 8] = *(const bf16x8*)&sp2[slot * 8];
            }
        }
        __syncthreads();

        {
            const int mt = w >> 1, at = w & 1;
            f32x4 sacc = {0.f, 0.f, 0.f, 0.f};
            #pragma unroll
            for (int kp = 0; kp < 8; ++kp) {
                bf16x8 af  = *(const bf16x8*)&pn_s[((mt * 8 + kp) * 64 + l) * 8];
                bf16x8 bf_ = *(const bf16x8*)&an_s[((at * 8 + kp) * 64 + l) * 8];
                sacc = __builtin_amdgcn_mfma_f32_16x16x32_bf16(af, bf_, sacc, 0, 0, 0);
            }
            const int a = at * 16 + n15;
            #pragma unroll
            for (int r = 0; r < 4; ++r) {
                const int pcl = q * 4 + r;
                const int pcc = mt * 16 + pcl;
                float xvv = (a < Av) ? __expf(fmaxf(20.f * sacc[r], 0.f)) : 0.f;
                __bf16 h = (__bf16)xvv;
                Xa_s[mt * 512 + (pcl + 16 * (a >> 3)) * 8 + (a & 7)] = h;
                XaT_s[at * 512 + (n15 + 16 * (pcc >> 3)) * 8 + (pcc & 7)] = h;
            }
        }
        __syncthreads();

        f32x4 aacc[2][4];
        {
            bf16x8 xa0 = *(const bf16x8*)&Xa_s[l * 8];
            bf16x8 xa1 = *(const bf16x8*)&Xa_s[512 + l * 8];
            bf16x8 xt0 = *(const bf16x8*)&XaT_s[l * 8];
            bf16x8 xt1 = *(const bf16x8*)&XaT_s[512 + l * 8];
            #pragma unroll
            for (int n = 0; n < 4; ++n) {
                f32x4 z = {0.f, 0.f, 0.f, 0.f};
                aacc[0][n] = __builtin_amdgcn_mfma_f32_16x16x32_bf16(xa0, ab[n], z, 0, 0, 0);
                aacc[1][n] = __builtin_amdgcn_mfma_f32_16x16x32_bf16(xa1, ab[n], z, 0, 0, 0);
                bf16x8 pb = *(const bf16x8*)&pB_s[((w * 4 + n) * 64 + l) * 8];
                apacc[0][n] = __builtin_amdgcn_mfma_f32_16x16x32_bf16(xt0, pb, apacc[0][n], 0, 0, 0);
                apacc[1][n] = __builtin_amdgcn_mfma_f32_16x16x32_bf16(xt1, pb, apacc[1][n], 0, 0, 0);
            }
        }

        #pragma unroll
        for (int mt2 = 0; mt2 < 2; ++mt2)
            #pragma unroll
            for (int r = 0; r < 4; ++r) {
                float ssq = 0.f;
                #pragma unroll
                for (int n = 0; n < 4; ++n) { float vv = aacc[mt2][n][r]; ssq += vv * vv; }
                ssq += __shfl_xor(ssq, 1, 64);
                ssq += __shfl_xor(ssq, 2, 64);
                ssq += __shfl_xor(ssq, 4, 64);
                ssq += __shfl_xor(ssq, 8, 64);
                if (n15 == 0) red_s[(mt2 * 16 + q * 4 + r) * 4 + w] = ssq;
            }
        __syncthreads();
        if (tid < 32) {
            float s = red_s[tid * 4] + red_s[tid * 4 + 1] + red_s[tid * 4 + 2] + red_s[tid * 4 + 3];
            invn_s[tid] = 1.f / fmaxf(sqrtf(s), 1e-12f);
        }
        __syncthreads();
        #pragma unroll
        for (int mt2 = 0; mt2 < 2; ++mt2)
            #pragma unroll
            for (int r = 0; r < 4; ++r) {
                const float inr = invn_s[mt2 * 16 + q * 4 + r];
                #pragma unroll
                for (int n = 0; n < 4; ++n) sa_acc[n] += aacc[mt2][n][r] * inr;
            }
    }

    #pragma unroll
    for (int mt2 = 0; mt2 < 2; ++mt2)
        #pragma unroll
        for (int r = 0; r < 4; ++r) {
            float ssq = 0.f;
            #pragma unroll
            for (int n = 0; n < 4; ++n) { float vv = apacc[mt2][n][r]; ssq += vv * vv; }
            ssq += __shfl_xor(ssq, 1, 64);
            ssq += __shfl_xor(ssq, 2, 64);
            ssq += __shfl_xor(ssq, 4, 64);
            ssq += __shfl_xor(ssq, 8, 64);
            if (n15 == 0) red_s[(mt2 * 16 + q * 4 + r) * 4 + w] = ssq;
        }
    __syncthreads();
    if (tid < 32) {
        float s = red_s[tid * 4] + red_s[tid * 4 + 1] + red_s[tid * 4 + 2] + red_s[tid * 4 + 3];
        invn_s[tid] = 1.f / fmaxf(sqrtf(s), 1e-12f);
    }
    __syncthreads();

    float prod = 0.f;
    #pragma unroll
    for (int n = 0; n < 4; ++n) {
        float sp = 0.f;
        #pragma unroll
        for (int mt2 = 0; mt2 < 2; ++mt2)
            #pragma unroll
            for (int r = 0; r < 4; ++r)
                sp += apacc[mt2][n][r] * invn_s[mt2 * 16 + q * 4 + r];
        float saf = sa_acc[n];
        saf += __shfl_xor(saf, 16, 64);
        saf += __shfl_xor(saf, 32, 64);
        float spf = sp;
        spf += __shfl_xor(spf, 16, 64);
        spf += __shfl_xor(spf, 32, 64);
        prod += saf * spf;
    }
    prod += __shfl_xor(prod, 1, 64);
    prod += __shfl_xor(prod, 2, 64);
    prod += __shfl_xor(prod, 4, 64);
    prod += __shfl_xor(prod, 8, 64);
    prod += __shfl_xor(prod, 16, 64);
    prod += __shfl_xor(prod, 32, 64);
    if (l == 0) wred_s[w] = prod;
    __syncthreads();
    if (tid == 0)
        out_sim[t * NB + v] = (wred_s[0] + wred_s[1] + wred_s[2] + wred_s[3]) * 0.25f
                              / ((float)Av * 30.f);
}

// ---------------------------------------------------------------------------
extern "C" void kernel_launch(void* const* d_in, const int* in_sizes, int n_in,
                              void* d_out, int out_size, void* d_ws, size_t ws_size,
                              hipStream_t stream)
{
    const float* vf = (const float*)d_in[0];
    const float* tf = (const float*)d_in[1];
    const int*   an = (const int*)d_in[3];
    const float* Wv = (const float*)d_in[4];
    const float* bv = (const float*)d_in[5];
    const float* Wt = (const float*)d_in[6];
    const float* bt = (const float*)d_in[7];
    const float* Wp = (const float*)d_in[8];
    const float* bp = (const float*)d_in[9];
    const float* Wa = (const float*)d_in[10];
    const float* ba = (const float*)d_in[11];

    float* out = (float*)d_out;
    float* out_vis = out;
    float* out_txt = out + 8192;
    float* out_pm  = out + 16384;
    float* out_am  = out + 24576;
    float* out_sim = out + 32768;

    float* Yws = (float*)d_ws;                      // 7232*256 f32 = 7,405,568 B
    __bf16* wsb = (__bf16*)((float*)d_ws + 7232 * 256);
    __bf16* pn_frag   = wsb;                        // 32*6*8192
    __bf16* pB_frag   = wsb + 1572864;
    __bf16* an_frag   = wsb + 3145728;              // 32*8192
    __bf16* attT_frag = wsb + 3407872;              // frags total 7,340,032 B

    hipMemsetAsync((char*)d_out + 16384 * sizeof(float), 0, 8192 * sizeof(float), stream);

    gemm_kernel<<<452 * 4, 256, 0, stream>>>(vf, tf, Wv, Wt, Wp, Wa, Yws);

    pack_kernel<<<226, 256, 0, stream>>>(
        Yws, bv, bt, bp, ba, an,
        out_vis, out_txt, out_pm, out_am,
        pn_frag, pB_frag, an_frag, attT_frag);

    pair_mfma_kernel<<<dim3(NB, NB), 256, 0, stream>>>(
        pn_frag, pB_frag, an_frag, attT_frag, an, out_sim);
}

// Round 6
// 154.669 us; speedup vs baseline: 1.4302x; 1.4302x over previous
//
#include <hip/hip_runtime.h>
#include <math.h>

#define D_IN 768
#define E_DIM 256
#define NB 32
#define NP 192
#define NA 30

#define A_SLOTS (452 * 24 * 64)          // 694,272
#define B_SLOTS (4 * 16 * 24 * 64)       // 98,304

typedef __attribute__((ext_vector_type(8))) __bf16 bf16x8;
typedef __attribute__((ext_vector_type(4))) float f32x4;

__device__ __forceinline__ bf16x8 cvt8(float4 a, float4 b) {
    bf16x8 v;
    v[0]=(__bf16)a.x; v[1]=(__bf16)a.y; v[2]=(__bf16)a.z; v[3]=(__bf16)a.w;
    v[4]=(__bf16)b.x; v[5]=(__bf16)b.y; v[6]=(__bf16)b.z; v[7]=(__bf16)b.w;
    return v;
}

// ---------------------------------------------------------------------------
// Prepack: fp32 sources -> bf16 MFMA fragment layouts.
// A slot s: r16 = s/1536, kt = (s%1536)>>6, l = s&63.
//   value_j = Xrow(r16, l&15)[kt*32 + (l>>4)*8 + j] -> Apack[s*8 + j]
// Row space (16-row groups r16 = 0..451):
//   [0,384)   patch: v=r16/12, sub=r16%12 -> vf[v*193 + 1 + sub*16 + i]
//   [384,448) att:   t=(r16-384)/2, half  -> tf[t*31 + 1 + half*16+i] (i>=30 dup 0)
//   448,449   vis CLS; 450,451 txt CLS
// B slot u: mat = u/24576, ntile = (u%24576)/1536, kt, l.
//   value_j = Wmat[ntile*16 + (l&15)][kt*32 + (l>>4)*8 + j] -> Bpack[u*8 + j]
// mat order: 0=Wp, 1=Wa, 2=Wv, 3=Wt.
// ---------------------------------------------------------------------------
__global__ __launch_bounds__(256) void prepack_kernel(
    const float* __restrict__ vf, const float* __restrict__ tf,
    const float* __restrict__ Wp, const float* __restrict__ Wa,
    const float* __restrict__ Wv, const float* __restrict__ Wt,
    __bf16* __restrict__ Apack, __bf16* __restrict__ Bpack)
{
    const int s = blockIdx.x * 256 + threadIdx.x;
    if (s < A_SLOTS) {
        const int r16 = s / 1536;
        const int rem = s - r16 * 1536;
        const int kt = rem >> 6, l = rem & 63;
        const int row16 = l & 15;
        const int k0 = kt * 32 + (l >> 4) * 8;
        const float* src;
        if (r16 < 384) {
            const int v = r16 / 12, sub = r16 - 12 * v;
            src = vf + (size_t)(v * 193 + 1 + sub * 16 + row16) * D_IN;
        } else if (r16 < 448) {
            const int u = r16 - 384, t = u >> 1, half = u & 1;
            const int ridx = half * 16 + row16;
            const int r = (ridx < NA) ? ridx : 0;
            src = tf + (size_t)(t * 31 + 1 + r) * D_IN;
        } else if (r16 < 450) {
            src = vf + (size_t)((r16 - 448) * 16 + row16) * 193 * D_IN;
        } else {
            src = tf + (size_t)((r16 - 450) * 16 + row16) * 31 * D_IN;
        }
        float4 f0 = *(const float4*)&src[k0];
        float4 f1 = *(const float4*)&src[k0 + 4];
        *(bf16x8*)&Apack[(size_t)s * 8] = cvt8(f0, f1);
    } else {
        const int u = s - A_SLOTS;
        const int mat = u / 24576;
        const int rem = u - mat * 24576;
        const int ntile = rem / 1536;
        const int rem2 = rem - ntile * 1536;
        const int kt = rem2 >> 6, l = rem2 & 63;
        const float* W;
        if (mat == 0)      W = Wp;
        else if (mat == 1) W = Wa;
        else if (mat == 2) W = Wv;
        else               W = Wt;
        const int k0 = kt * 32 + (l >> 4) * 8;
        const float* src = W + (size_t)(ntile * 16 + (l & 15)) * D_IN;
        float4 f0 = *(const float4*)&src[k0];
        float4 f1 = *(const float4*)&src[k0 + 4];
        *(bf16x8*)&Bpack[(size_t)u * 8] = cvt8(f0, f1);
    }
}

// ---------------------------------------------------------------------------
// Fragment GEMM: Ybf[7232][256] (bf16, no bias). Block = (r16, cg); wave w
// computes tile (r16, ntg = cg*4+w): per kt, 2 coalesced dwordx4 loads + MFMA.
// ---------------------------------------------------------------------------
__global__ __launch_bounds__(256) void gemm_frag_kernel(
    const __bf16* __restrict__ Apack, const __bf16* __restrict__ Bpack,
    __bf16* __restrict__ Ybf)
{
    const int bid = blockIdx.x;
    const int r16 = bid >> 2, cg = bid & 3;
    const int tid = threadIdx.x;
    const int w = tid >> 6, l = tid & 63, q = l >> 4, n15 = l & 15;
    const int ntg = cg * 4 + w;
    const int mat = (r16 < 384) ? 0 : (r16 < 448) ? 1 : (r16 < 450) ? 2 : 3;

    const __bf16* Ab = Apack + (size_t)r16 * 24 * 512 + l * 8;
    const __bf16* Bb = Bpack + (size_t)(mat * 16 + ntg) * 24 * 512 + l * 8;

    f32x4 acc = {0.f, 0.f, 0.f, 0.f};
    #pragma unroll 8
    for (int kt = 0; kt < 24; ++kt) {
        bf16x8 a = *(const bf16x8*)&Ab[kt * 512];
        bf16x8 b = *(const bf16x8*)&Bb[kt * 512];
        acc = __builtin_amdgcn_mfma_f32_16x16x32_bf16(a, b, acc, 0, 0, 0);
    }

    const int col = ntg * 16 + n15;
    #pragma unroll
    for (int r = 0; r < 4; ++r)
        Ybf[(size_t)(r16 * 16 + q * 4 + r) * E_DIM + col] = (__bf16)acc[r];
}

// ---------------------------------------------------------------------------
// Pack kernel: 226 blocks. Loads 32 bf16 Y rows (+bias) to LDS, then norms/
// means/embeds and bf16 fragment packs for the pair kernel:
//   pn_frag[v][c] : l2norm(patch) A-row-frag  [mt2][koct8][lane64][8]
//   pB_frag[v][c] : raw patch B-frag (k=p)    [nt16][lane64][8]
//   an_frag[t]    : l2norm(att) row-frag      [at2][koct8][lane64][8]
//   attT_frag[t]  : raw att B-frag (k=a)      [nt16][lane64][8]
// ---------------------------------------------------------------------------
__global__ __launch_bounds__(256) void pack_kernel(
    const __bf16* __restrict__ Ybf,
    const float* __restrict__ bv, const float* __restrict__ bt,
    const float* __restrict__ bp, const float* __restrict__ ba,
    const int* __restrict__ att_nums,
    float* __restrict__ out_vis, float* __restrict__ out_txt,
    float* __restrict__ out_pm, float* __restrict__ out_am,
    __bf16* __restrict__ pn_frag, __bf16* __restrict__ pB_frag,
    __bf16* __restrict__ an_frag, __bf16* __restrict__ attT_frag)
{
    __shared__ float LDSf[32 * 260];
    __shared__ float invn_s[32];

    const int bid = blockIdx.x;
    const int tid = threadIdx.x;

    int role, base;
    const float* bias;
    if (bid < 192)       { role = 0; base = 32 * bid;              bias = bp; }
    else if (bid < 224)  { role = 1; base = 6144 + 32 * (bid-192); bias = ba; }
    else if (bid == 224) { role = 2; base = 7168;                  bias = bv; }
    else                 { role = 3; base = 7200;                  bias = bt; }

    if (role >= 2) {
        float* outp = (role == 2) ? out_vis : out_txt;
        const float b = bias[tid];
        #pragma unroll
        for (int i = 0; i < 32; ++i)
            outp[i * E_DIM + tid] = (float)Ybf[(size_t)(base + i) * E_DIM + tid] + b;
        return;
    }

    {
        const float b = bias[tid];
        #pragma unroll
        for (int i = 0; i < 32; ++i)
            LDSf[i * 260 + tid] = (float)Ybf[(size_t)(base + i) * E_DIM + tid] + b;
    }
    __syncthreads();

    if (role == 0) {
        const int v = bid / 6, c = bid - 6 * v;
        {
            const int row = tid >> 3, seg = tid & 7;
            const float* rr = &LDSf[row * 260 + seg * 32];
            float ssq = 0.f;
            #pragma unroll
            for (int j = 0; j < 32; ++j) ssq += rr[j] * rr[j];
            ssq += __shfl_xor(ssq, 1, 64);
            ssq += __shfl_xor(ssq, 2, 64);
            ssq += __shfl_xor(ssq, 4, 64);
            if (seg == 0) invn_s[row] = 1.f / fmaxf(sqrtf(ssq), 1e-12f);
        }
        {
            float s = 0.f;
            #pragma unroll
            for (int r = 0; r < 32; ++r) s += LDSf[r * 260 + tid];
            atomicAdd(&out_pm[v * E_DIM + tid], s * (1.f / 192.f));
        }
        __syncthreads();
        __bf16* dstn = pn_frag + (size_t)(v * 6 + c) * 8192;
        #pragma unroll
        for (int i = 0; i < 4; ++i) {
            const int slot = tid + 256 * i;
            const int mt = slot >> 9, koct = (slot >> 6) & 7, lane = slot & 63;
            const int prl = mt * 16 + (lane & 15);
            const int e0 = koct * 32 + (lane >> 4) * 8;
            const float inr = invn_s[prl];
            const float* src = &LDSf[prl * 260 + e0];
            bf16x8 vv;
            #pragma unroll
            for (int j = 0; j < 8; ++j) vv[j] = (__bf16)(src[j] * inr);
            *(bf16x8*)&dstn[slot * 8] = vv;
        }
        __bf16* dstb = pB_frag + (size_t)(v * 6 + c) * 8192;
        #pragma unroll
        for (int i = 0; i < 4; ++i) {
            const int slot = tid + 256 * i;
            const int nt = slot >> 6, lane = slot & 63;
            const int e = nt * 16 + (lane & 15);
            const int p0 = (lane >> 4) * 8;
            bf16x8 vv;
            #pragma unroll
            for (int j = 0; j < 8; ++j) vv[j] = (__bf16)LDSf[(p0 + j) * 260 + e];
            *(bf16x8*)&dstb[slot * 8] = vv;
        }
    } else {
        const int t = bid - 192;
        const int Av = att_nums[t];
        {
            const int row = tid >> 3, seg = tid & 7;
            const float* rr = &LDSf[row * 260 + seg * 32];
            float ssq = 0.f;
            #pragma unroll
            for (int j = 0; j < 32; ++j) ssq += rr[j] * rr[j];
            ssq += __shfl_xor(ssq, 1, 64);
            ssq += __shfl_xor(ssq, 2, 64);
            ssq += __shfl_xor(ssq, 4, 64);
            if (seg == 0) invn_s[row] = (row < NA) ? 1.f / fmaxf(sqrtf(ssq), 1e-12f) : 0.f;
        }
        {
            float s = 0.f;
            #pragma unroll
            for (int r = 0; r < NA; ++r) s += LDSf[r * 260 + tid];
            out_am[t * E_DIM + tid] = s / (float)Av;
        }
        __syncthreads();
        __bf16* dstn = an_frag + (size_t)t * 8192;
        #pragma unroll
        for (int i = 0; i < 4; ++i) {
            const int slot = tid + 256 * i;
            const int at = slot >> 9, koct = (slot >> 6) & 7, lane = slot & 63;
            const int a = at * 16 + (lane & 15);
            const int e0 = koct * 32 + (lane >> 4) * 8;
            const float inr = (a < NA) ? invn_s[a] : 0.f;
            const float* src = &LDSf[a * 260 + e0];
            bf16x8 vv;
            #pragma unroll
            for (int j = 0; j < 8; ++j) vv[j] = (__bf16)(src[j] * inr);
            *(bf16x8*)&dstn[slot * 8] = vv;
        }
        __bf16* dstb = attT_frag + (size_t)t * 8192;
        #pragma unroll
        for (int i = 0; i < 4; ++i) {
            const int slot = tid + 256 * i;
            const int nt = slot >> 6, lane = slot & 63;
            const int e = nt * 16 + (lane & 15);
            const int a0 = (lane >> 4) * 8;
            bf16x8 vv;
            #pragma unroll
            for (int j = 0; j < 8; ++j)
                vv[j] = (a0 + j < NA) ? (__bf16)LDSf[(a0 + j) * 260 + e] : (__bf16)0.f;
            *(bf16x8*)&dstb[slot * 8] = vv;
        }
    }
}

// ---------------------------------------------------------------------------
// MFMA pair kernel: one block per (v,t). All staging = contiguous 16B copies.
// ---------------------------------------------------------------------------
__global__ __launch_bounds__(256) void pair_mfma_kernel(
    const __bf16* __restrict__ pn_frag, const __bf16* __restrict__ pB_frag,
    const __bf16* __restrict__ an_frag, const __bf16* __restrict__ attT_frag,
    const int* __restrict__ att_nums, float* __restrict__ out_sim)
{
    __shared__ __align__(16) __bf16 an_s[8192];
    __shared__ __align__(16) __bf16 attT_s[8192];
    __shared__ __align__(16) __bf16 pn_s[8192];
    __shared__ __align__(16) __bf16 pB_s[8192];
    __shared__ __align__(16) __bf16 Xa_s[1024];
    __shared__ __align__(16) __bf16 XaT_s[1024];
    __shared__ float red_s[128];
    __shared__ float invn_s[32];
    __shared__ float wred_s[4];

    const int v = blockIdx.x, t = blockIdx.y;
    const int tid = threadIdx.x;
    const int w = tid >> 6, l = tid & 63, q = l >> 4, n15 = l & 15;
    const int Av = att_nums[t];

    {
        const __bf16* s1 = an_frag + (size_t)t * 8192;
        const __bf16* s2 = attT_frag + (size_t)t * 8192;
        #pragma unroll
        for (int i = 0; i < 4; ++i) {
            const int slot = tid + 256 * i;
            *(bf16x8*)&an_s[slot * 8]   = *(const bf16x8*)&s1[slot * 8];
            *(bf16x8*)&attT_s[slot * 8] = *(const bf16x8*)&s2[slot * 8];
        }
    }
    __syncthreads();

    bf16x8 ab[4];
    #pragma unroll
    for (int n = 0; n < 4; ++n)
        ab[n] = *(const bf16x8*)&attT_s[((w * 4 + n) * 64 + l) * 8];

    f32x4 apacc[2][4];
    #pragma unroll
    for (int m = 0; m < 2; ++m)
        #pragma unroll
        for (int n = 0; n < 4; ++n) { f32x4 z = {0.f,0.f,0.f,0.f}; apacc[m][n] = z; }
    float sa_acc[4] = {0.f, 0.f, 0.f, 0.f};

    for (int c = 0; c < 6; ++c) {
        __syncthreads();
        {
            const __bf16* sp1 = pn_frag + (size_t)(v * 6 + c) * 8192;
            const __bf16* sp2 = pB_frag + (size_t)(v * 6 + c) * 8192;
            #pragma unroll
            for (int i = 0; i < 4; ++i) {
                const int slot = tid + 256 * i;
                *(bf16x8*)&pn_s[slot * 8] = *(const bf16x8*)&sp1[slot * 8];
                *(bf16x8*)&pB_s[slot * 8] = *(const bf16x8*)&sp2[slot * 8];
            }
        }
        __syncthreads();

        {
            const int mt = w >> 1, at = w & 1;
            f32x4 sacc = {0.f, 0.f, 0.f, 0.f};
            #pragma unroll
            for (int kp = 0; kp < 8; ++kp) {
                bf16x8 af  = *(const bf16x8*)&pn_s[((mt * 8 + kp) * 64 + l) * 8];
                bf16x8 bf_ = *(const bf16x8*)&an_s[((at * 8 + kp) * 64 + l) * 8];
                sacc = __builtin_amdgcn_mfma_f32_16x16x32_bf16(af, bf_, sacc, 0, 0, 0);
            }
            const int a = at * 16 + n15;
            #pragma unroll
            for (int r = 0; r < 4; ++r) {
                const int pcl = q * 4 + r;
                const int pcc = mt * 16 + pcl;
                float xvv = (a < Av) ? __expf(fmaxf(20.f * sacc[r], 0.f)) : 0.f;
                __bf16 h = (__bf16)xvv;
                Xa_s[mt * 512 + (pcl + 16 * (a >> 3)) * 8 + (a & 7)] = h;
                XaT_s[at * 512 + (n15 + 16 * (pcc >> 3)) * 8 + (pcc & 7)] = h;
            }
        }
        __syncthreads();

        f32x4 aacc[2][4];
        {
            bf16x8 xa0 = *(const bf16x8*)&Xa_s[l * 8];
            bf16x8 xa1 = *(const bf16x8*)&Xa_s[512 + l * 8];
            bf16x8 xt0 = *(const bf16x8*)&XaT_s[l * 8];
            bf16x8 xt1 = *(const bf16x8*)&XaT_s[512 + l * 8];
            #pragma unroll
            for (int n = 0; n < 4; ++n) {
                f32x4 z = {0.f, 0.f, 0.f, 0.f};
                aacc[0][n] = __builtin_amdgcn_mfma_f32_16x16x32_bf16(xa0, ab[n], z, 0, 0, 0);
                aacc[1][n] = __builtin_amdgcn_mfma_f32_16x16x32_bf16(xa1, ab[n], z, 0, 0, 0);
                bf16x8 pb = *(const bf16x8*)&pB_s[((w * 4 + n) * 64 + l) * 8];
                apacc[0][n] = __builtin_amdgcn_mfma_f32_16x16x32_bf16(xt0, pb, apacc[0][n], 0, 0, 0);
                apacc[1][n] = __builtin_amdgcn_mfma_f32_16x16x32_bf16(xt1, pb, apacc[1][n], 0, 0, 0);
            }
        }

        #pragma unroll
        for (int mt2 = 0; mt2 < 2; ++mt2)
            #pragma unroll
            for (int r = 0; r < 4; ++r) {
                float ssq = 0.f;
                #pragma unroll
                for (int n = 0; n < 4; ++n) { float vv = aacc[mt2][n][r]; ssq += vv * vv; }
                ssq += __shfl_xor(ssq, 1, 64);
                ssq += __shfl_xor(ssq, 2, 64);
                ssq += __shfl_xor(ssq, 4, 64);
                ssq += __shfl_xor(ssq, 8, 64);
                if (n15 == 0) red_s[(mt2 * 16 + q * 4 + r) * 4 + w] = ssq;
            }
        __syncthreads();
        if (tid < 32) {
            float s = red_s[tid * 4] + red_s[tid * 4 + 1] + red_s[tid * 4 + 2] + red_s[tid * 4 + 3];
            invn_s[tid] = 1.f / fmaxf(sqrtf(s), 1e-12f);
        }
        __syncthreads();
        #pragma unroll
        for (int mt2 = 0; mt2 < 2; ++mt2)
            #pragma unroll
            for (int r = 0; r < 4; ++r) {
                const float inr = invn_s[mt2 * 16 + q * 4 + r];
                #pragma unroll
                for (int n = 0; n < 4; ++n) sa_acc[n] += aacc[mt2][n][r] * inr;
            }
    }

    #pragma unroll
    for (int mt2 = 0; mt2 < 2; ++mt2)
        #pragma unroll
        for (int r = 0; r < 4; ++r) {
            float ssq = 0.f;
            #pragma unroll
            for (int n = 0; n < 4; ++n) { float vv = apacc[mt2][n][r]; ssq += vv * vv; }
            ssq += __shfl_xor(ssq, 1, 64);
            ssq += __shfl_xor(ssq, 2, 64);
            ssq += __shfl_xor(ssq, 4, 64);
            ssq += __shfl_xor(ssq, 8, 64);
            if (n15 == 0) red_s[(mt2 * 16 + q * 4 + r) * 4 + w] = ssq;
        }
    __syncthreads();
    if (tid < 32) {
        float s = red_s[tid * 4] + red_s[tid * 4 + 1] + red_s[tid * 4 + 2] + red_s[tid * 4 + 3];
        invn_s[tid] = 1.f / fmaxf(sqrtf(s), 1e-12f);
    }
    __syncthreads();

    float prod = 0.f;
    #pragma unroll
    for (int n = 0; n < 4; ++n) {
        float sp = 0.f;
        #pragma unroll
        for (int mt2 = 0; mt2 < 2; ++mt2)
            #pragma unroll
            for (int r = 0; r < 4; ++r)
                sp += apacc[mt2][n][r] * invn_s[mt2 * 16 + q * 4 + r];
        float saf = sa_acc[n];
        saf += __shfl_xor(saf, 16, 64);
        saf += __shfl_xor(saf, 32, 64);
        float spf = sp;
        spf += __shfl_xor(spf, 16, 64);
        spf += __shfl_xor(spf, 32, 64);
        prod += saf * spf;
    }
    prod += __shfl_xor(prod, 1, 64);
    prod += __shfl_xor(prod, 2, 64);
    prod += __shfl_xor(prod, 4, 64);
    prod += __shfl_xor(prod, 8, 64);
    prod += __shfl_xor(prod, 16, 64);
    prod += __shfl_xor(prod, 32, 64);
    if (l == 0) wred_s[w] = prod;
    __syncthreads();
    if (tid == 0)
        out_sim[t * NB + v] = (wred_s[0] + wred_s[1] + wred_s[2] + wred_s[3]) * 0.25f
                              / ((float)Av * 30.f);
}

// ---------------------------------------------------------------------------
extern "C" void kernel_launch(void* const* d_in, const int* in_sizes, int n_in,
                              void* d_out, int out_size, void* d_ws, size_t ws_size,
                              hipStream_t stream)
{
    const float* vf = (const float*)d_in[0];
    const float* tf = (const float*)d_in[1];
    const int*   an = (const int*)d_in[3];
    const float* Wv = (const float*)d_in[4];
    const float* bv = (const float*)d_in[5];
    const float* Wt = (const float*)d_in[6];
    const float* bt = (const float*)d_in[7];
    const float* Wp = (const float*)d_in[8];
    const float* bp = (const float*)d_in[9];
    const float* Wa = (const float*)d_in[10];
    const float* ba = (const float*)d_in[11];

    float* out = (float*)d_out;
    float* out_vis = out;
    float* out_txt = out + 8192;
    float* out_pm  = out + 16384;
    float* out_am  = out + 24576;
    float* out_sim = out + 32768;

    // ws layout (lifetimes overlapped):
    //   [0, 3,702,784)            Ybf  (7232x256 bf16)          [gemm -> pack]
    //   region2 = ws + 3,702,784:
    //     Apack 11,108,352 B + Bpack 1,572,864 B                [prepack -> gemm]
    //     frags 7,340,032 B  (overlays Apack)                   [pack -> pair]
    // total required: 16,384,000 B
    __bf16* Ybf = (__bf16*)d_ws;
    char* region2 = (char*)d_ws + 3702784;
    __bf16* Apack = (__bf16*)region2;                   // 5,554,176 elems
    __bf16* Bpack = Apack + (size_t)A_SLOTS * 8;        // 786,432 elems
    __bf16* pn_frag   = (__bf16*)region2;               // 1,572,864 elems
    __bf16* pB_frag   = pn_frag + 1572864;              // 1,572,864 elems
    __bf16* an_frag   = pn_frag + 3145728;              // 262,144 elems
    __bf16* attT_frag = pn_frag + 3407872;              // 262,144 elems

    hipMemsetAsync((char*)d_out + 16384 * sizeof(float), 0, 8192 * sizeof(float), stream);

    prepack_kernel<<<(A_SLOTS + B_SLOTS) / 256, 256, 0, stream>>>(
        vf, tf, Wp, Wa, Wv, Wt, Apack, Bpack);

    gemm_frag_kernel<<<452 * 4, 256, 0, stream>>>(Apack, Bpack, Ybf);

    pack_kernel<<<226, 256, 0, stream>>>(
        Ybf, bv, bt, bp, ba, an,
        out_vis, out_txt, out_pm, out_am,
        pn_frag, pB_frag, an_frag, attT_frag);

    pair_mfma_kernel<<<dim3(NB, NB), 256, 0, stream>>>(
        pn_frag, pB_frag, an_frag, attT_frag, an, out_sim);
}

// Round 7
// 149.569 us; speedup vs baseline: 1.4789x; 1.0341x over previous
//
#include <hip/hip_runtime.h>
#include <math.h>

#define D_IN 768
#define E_DIM 256
#define NB 32
#define NP 192
#define NA 30

#define A_SLOTS (452 * 24 * 64)          // 694,272
#define B_SLOTS (4 * 16 * 24 * 64)       // 98,304

typedef __attribute__((ext_vector_type(8))) __bf16 bf16x8;
typedef __attribute__((ext_vector_type(4))) float f32x4;

__device__ __forceinline__ bf16x8 cvt8(float4 a, float4 b) {
    bf16x8 v;
    v[0]=(__bf16)a.x; v[1]=(__bf16)a.y; v[2]=(__bf16)a.z; v[3]=(__bf16)a.w;
    v[4]=(__bf16)b.x; v[5]=(__bf16)b.y; v[6]=(__bf16)b.z; v[7]=(__bf16)b.w;
    return v;
}

// ---------------------------------------------------------------------------
// Prepack: fp32 sources -> bf16 MFMA fragment layouts; also zeroes the
// out_pm/out_am region (atomics accumulate into it later).
// A slot s: r16 = s/1536, kt, l.  value_j = Xrow(r16, l&15)[kt*32+(l>>4)*8+j]
// B slot u: mat(4) x ntile(16) x kt(24) x lane(64). mat: 0=Wp,1=Wa,2=Wv,3=Wt.
// ---------------------------------------------------------------------------
__global__ __launch_bounds__(256) void prepack_kernel(
    const float* __restrict__ vf, const float* __restrict__ tf,
    const float* __restrict__ Wp, const float* __restrict__ Wa,
    const float* __restrict__ Wv, const float* __restrict__ Wt,
    __bf16* __restrict__ Apack, __bf16* __restrict__ Bpack,
    float* __restrict__ out_zero)
{
    const int s = blockIdx.x * 256 + threadIdx.x;
    if (s < 16384) out_zero[s] = 0.f;    // out_pm + out_am
    if (s < A_SLOTS) {
        const int r16 = s / 1536;
        const int rem = s - r16 * 1536;
        const int kt = rem >> 6, l = rem & 63;
        const int row16 = l & 15;
        const int k0 = kt * 32 + (l >> 4) * 8;
        const float* src;
        if (r16 < 384) {
            const int v = r16 / 12, sub = r16 - 12 * v;
            src = vf + (size_t)(v * 193 + 1 + sub * 16 + row16) * D_IN;
        } else if (r16 < 448) {
            const int u = r16 - 384, t = u >> 1, half = u & 1;
            const int ridx = half * 16 + row16;
            const int r = (ridx < NA) ? ridx : 0;
            src = tf + (size_t)(t * 31 + 1 + r) * D_IN;
        } else if (r16 < 450) {
            src = vf + (size_t)((r16 - 448) * 16 + row16) * 193 * D_IN;
        } else {
            src = tf + (size_t)((r16 - 450) * 16 + row16) * 31 * D_IN;
        }
        float4 f0 = *(const float4*)&src[k0];
        float4 f1 = *(const float4*)&src[k0 + 4];
        *(bf16x8*)&Apack[(size_t)s * 8] = cvt8(f0, f1);
    } else {
        const int u = s - A_SLOTS;
        const int mat = u / 24576;
        const int rem = u - mat * 24576;
        const int ntile = rem / 1536;
        const int rem2 = rem - ntile * 1536;
        const int kt = rem2 >> 6, l = rem2 & 63;
        const float* W;
        if (mat == 0)      W = Wp;
        else if (mat == 1) W = Wa;
        else if (mat == 2) W = Wv;
        else               W = Wt;
        const int k0 = kt * 32 + (l >> 4) * 8;
        const float* src = W + (size_t)(ntile * 16 + (l & 15)) * D_IN;
        float4 f0 = *(const float4*)&src[k0];
        float4 f1 = *(const float4*)&src[k0 + 4];
        *(bf16x8*)&Bpack[(size_t)u * 8] = cvt8(f0, f1);
    }
}

// ---------------------------------------------------------------------------
// Fused GEMM+pack: grid 452 blocks. Block r16 computes its 16 rows x full 256
// cols (wave w: cols w*64..w*64+63, 4 tiles, K=768), then bias/norms/means/
// embeds and writes the bf16 fragment tensors directly from fp32 accs:
//   pn_frag[v][c] (mt half) : l2norm(patch) A-row-frag [mt2][koct8][lane64][8]
//   pB_frag[v][c] (lane half): raw patch B-frag (k=p)  [nt16][lane64][8]
//   an_frag[t], attT_frag[t]: same for att (rows >=30 zero)
// ---------------------------------------------------------------------------
__global__ __launch_bounds__(256) void gemm_pack_kernel(
    const __bf16* __restrict__ Apack, const __bf16* __restrict__ Bpack,
    const float* __restrict__ bv, const float* __restrict__ bt,
    const float* __restrict__ bp, const float* __restrict__ ba,
    const int* __restrict__ att_nums,
    float* __restrict__ out_vis, float* __restrict__ out_txt,
    float* __restrict__ out_pm, float* __restrict__ out_am,
    __bf16* __restrict__ pn_frag, __bf16* __restrict__ pB_frag,
    __bf16* __restrict__ an_frag, __bf16* __restrict__ attT_frag)
{
    __shared__ float LDSf[16 * 260];
    __shared__ float invn_s[16];

    const int r16 = blockIdx.x;
    const int tid = threadIdx.x;
    const int w = tid >> 6, l = tid & 63, q = l >> 4, n15 = l & 15;
    const int mat = (r16 < 384) ? 0 : (r16 < 448) ? 1 : (r16 < 450) ? 2 : 3;
    const float* bias = (mat == 0) ? bp : (mat == 1) ? ba : (mat == 2) ? bv : bt;

    const __bf16* Ab = Apack + (size_t)r16 * 24 * 512 + l * 8;
    const __bf16* Bb = Bpack + ((size_t)(mat * 16 + w * 4) * 24 * 512) + l * 8;

    f32x4 acc[4];
    #pragma unroll
    for (int n = 0; n < 4; ++n) { f32x4 z = {0.f,0.f,0.f,0.f}; acc[n] = z; }

    #pragma unroll 6
    for (int kt = 0; kt < 24; ++kt) {
        bf16x8 a = *(const bf16x8*)&Ab[kt * 512];
        #pragma unroll
        for (int nt = 0; nt < 4; ++nt) {
            bf16x8 b = *(const bf16x8*)&Bb[(size_t)nt * 24 * 512 + kt * 512];
            acc[nt] = __builtin_amdgcn_mfma_f32_16x16x32_bf16(a, b, acc[nt], 0, 0, 0);
        }
    }

    // spill (+bias) to LDSf[16][260]
    #pragma unroll
    for (int nt = 0; nt < 4; ++nt) {
        const int col = w * 64 + nt * 16 + n15;
        const float b = bias[col];
        #pragma unroll
        for (int r = 0; r < 4; ++r)
            LDSf[(q * 4 + r) * 260 + col] = acc[nt][r] + b;
    }
    __syncthreads();

    if (mat >= 2) {   // embeds
        float* outp = (mat == 2) ? out_vis : out_txt;
        const int rowbase = (mat == 2) ? (r16 - 448) * 16 : (r16 - 450) * 16;
        #pragma unroll
        for (int i = 0; i < 16; ++i)
            outp[(rowbase + i) * E_DIM + tid] = LDSf[i * 260 + tid];
        return;
    }

    const bool is_patch = (mat == 0);
    int vc = 0, mt = 0, t = 0, Av = 1;
    if (is_patch) {
        const int v = r16 / 12, sub = r16 - 12 * v;
        vc = v * 6 + (sub >> 1);  mt = sub & 1;
    } else {
        const int u = r16 - 384;
        t = u >> 1;  mt = u & 1;  Av = att_nums[t];
    }

    // row inv-norms (16 rows; att rows with global a>=30 -> 0)
    {
        const int row = tid >> 4, seg = tid & 15;
        const float* rr = &LDSf[row * 260 + seg * 16];
        float ssq = 0.f;
        #pragma unroll
        for (int j = 0; j < 16; ++j) ssq += rr[j] * rr[j];
        ssq += __shfl_xor(ssq, 1, 64);
        ssq += __shfl_xor(ssq, 2, 64);
        ssq += __shfl_xor(ssq, 4, 64);
        ssq += __shfl_xor(ssq, 8, 64);
        if (seg == 0) {
            const bool valid = is_patch || (mt * 16 + row < NA);
            invn_s[row] = valid ? 1.f / fmaxf(sqrtf(ssq), 1e-12f) : 0.f;
        }
    }
    // means (atomic partials; out_pm/out_am zeroed by prepack)
    {
        const int nrows = is_patch ? 16 : (mt == 0 ? 16 : 14);
        float s = 0.f;
        for (int r = 0; r < nrows; ++r) s += LDSf[r * 260 + tid];
        if (is_patch) atomicAdd(&out_pm[(r16 / 12) * E_DIM + tid], s * (1.f / 192.f));
        else          atomicAdd(&out_am[t * E_DIM + tid], s / (float)Av);
    }
    __syncthreads();

    // normalized A-row-frag (mt half: 512 slots, 2 per thread)
    {
        __bf16* dstn = (is_patch ? pn_frag + (size_t)vc * 8192
                                 : an_frag + (size_t)t * 8192) + (size_t)mt * 4096;
        #pragma unroll
        for (int ii = 0; ii < 2; ++ii) {
            const int s2 = tid + 256 * ii;
            const int koct = s2 >> 6, lane = s2 & 63;
            const int rloc = lane & 15;
            const int e0 = koct * 32 + (lane >> 4) * 8;
            const float inr = invn_s[rloc];
            const float* src = &LDSf[rloc * 260 + e0];
            bf16x8 vv;
            #pragma unroll
            for (int j = 0; j < 8; ++j) vv[j] = (__bf16)(src[j] * inr);
            *(bf16x8*)&dstn[(size_t)s2 * 8] = vv;
        }
    }
    // raw B-frag (k=row): lanes [32*mt, 32*mt+32) of each nt; 512 slots, 2/thread
    {
        __bf16* dstb = is_patch ? pB_frag + (size_t)vc * 8192
                                : attT_frag + (size_t)t * 8192;
        #pragma unroll
        for (int ii = 0; ii < 2; ++ii) {
            const int s2 = tid + 256 * ii;
            const int nt = s2 >> 5, li = s2 & 31;
            const int lane = 32 * mt + li;
            const int p0 = (li >> 4) * 8;
            const int e = nt * 16 + (li & 15);
            bf16x8 vv;
            #pragma unroll
            for (int j = 0; j < 8; ++j) {
                float val = LDSf[(p0 + j) * 260 + e];
                if (!is_patch && (mt * 16 + p0 + j >= NA)) val = 0.f;
                vv[j] = (__bf16)val;
            }
            *(bf16x8*)&dstb[(size_t)(nt * 64 + lane) * 8] = vv;
        }
    }
}

// ---------------------------------------------------------------------------
// Pair kernel v3: one block per (v,t). LDS = an_s + X buffers only (~21 KB).
// pn A-frags read per-MFMA from global; pb/ab B-frags in registers.
// 2 barriers per chunk.
// ---------------------------------------------------------------------------
__global__ __launch_bounds__(256, 3) void pair_mfma_kernel(
    const __bf16* __restrict__ pn_frag, const __bf16* __restrict__ pB_frag,
    const __bf16* __restrict__ an_frag, const __bf16* __restrict__ attT_frag,
    const int* __restrict__ att_nums, float* __restrict__ out_sim)
{
    __shared__ __align__(16) __bf16 an_s[8192];
    __shared__ __align__(16) __bf16 Xa_s[1024];
    __shared__ __align__(16) __bf16 XaT_s[1024];
    __shared__ float red_s[128];
    __shared__ float wred_s[4];

    const int v = blockIdx.x, t = blockIdx.y;
    const int tid = threadIdx.x;
    const int w = tid >> 6, l = tid & 63, q = l >> 4, n15 = l & 15;
    const int Av = att_nums[t];
    const int mt = w >> 1, at = w & 1;

    {
        const __bf16* s1 = an_frag + (size_t)t * 8192;
        #pragma unroll
        for (int i = 0; i < 4; ++i) {
            const int slot = tid + 256 * i;
            *(bf16x8*)&an_s[slot * 8] = *(const bf16x8*)&s1[slot * 8];
        }
    }
    __syncthreads();

    const __bf16* atb = attT_frag + (size_t)t * 8192;

    f32x4 apacc[2][4];
    #pragma unroll
    for (int m = 0; m < 2; ++m)
        #pragma unroll
        for (int n = 0; n < 4; ++n) { f32x4 z = {0.f,0.f,0.f,0.f}; apacc[m][n] = z; }
    float sa_acc[4] = {0.f, 0.f, 0.f, 0.f};

    for (int c = 0; c < 6; ++c) {
        const __bf16* pnb = pn_frag + (size_t)(v * 6 + c) * 8192;
        const __bf16* pbb = pB_frag + (size_t)(v * 6 + c) * 8192;

        // B-operand register loads (used after sync2; issued early to pipeline)
        bf16x8 pb[4], ab[4];
        #pragma unroll
        for (int n = 0; n < 4; ++n) {
            pb[n] = *(const bf16x8*)&pbb[((w * 4 + n) * 64 + l) * 8];
            ab[n] = *(const bf16x8*)&atb[((w * 4 + n) * 64 + l) * 8];
        }

        // ---- score: S=cos, X=exp(relu(20S)) masked, both frag layouts ----
        {
            f32x4 sacc = {0.f, 0.f, 0.f, 0.f};
            #pragma unroll
            for (int kp = 0; kp < 8; ++kp) {
                bf16x8 af  = *(const bf16x8*)&pnb[((mt * 8 + kp) * 64 + l) * 8];
                bf16x8 bf_ = *(const bf16x8*)&an_s[((at * 8 + kp) * 64 + l) * 8];
                sacc = __builtin_amdgcn_mfma_f32_16x16x32_bf16(af, bf_, sacc, 0, 0, 0);
            }
            const int a = at * 16 + n15;
            #pragma unroll
            for (int r = 0; r < 4; ++r) {
                const int pcl = q * 4 + r;
                const int pcc = mt * 16 + pcl;
                float xvv = (a < Av) ? __expf(fmaxf(20.f * sacc[r], 0.f)) : 0.f;
                __bf16 h = (__bf16)xvv;
                Xa_s[mt * 512 + (pcl + 16 * (a >> 3)) * 8 + (a & 7)] = h;
                XaT_s[at * 512 + (n15 + 16 * (pcc >> 3)) * 8 + (pcc & 7)] = h;
            }
        }
        __syncthreads();   // sync2: Xa/XaT visible

        // ---- attend: aa = X·att, ap += X^T·patch ----
        f32x4 aacc[2][4];
        {
            bf16x8 xa0 = *(const bf16x8*)&Xa_s[l * 8];
            bf16x8 xa1 = *(const bf16x8*)&Xa_s[512 + l * 8];
            bf16x8 xt0 = *(const bf16x8*)&XaT_s[l * 8];
            bf16x8 xt1 = *(const bf16x8*)&XaT_s[512 + l * 8];
            #pragma unroll
            for (int n = 0; n < 4; ++n) {
                f32x4 z = {0.f, 0.f, 0.f, 0.f};
                aacc[0][n] = __builtin_amdgcn_mfma_f32_16x16x32_bf16(xa0, ab[n], z, 0, 0, 0);
                aacc[1][n] = __builtin_amdgcn_mfma_f32_16x16x32_bf16(xa1, ab[n], z, 0, 0, 0);
                apacc[0][n] = __builtin_amdgcn_mfma_f32_16x16x32_bf16(xt0, pb[n], apacc[0][n], 0, 0, 0);
                apacc[1][n] = __builtin_amdgcn_mfma_f32_16x16x32_bf16(xt1, pb[n], apacc[1][n], 0, 0, 0);
            }
        }
        // aa row-norm partials (4 e-tiles per wave) -> red_s
        #pragma unroll
        for (int mt2 = 0; mt2 < 2; ++mt2)
            #pragma unroll
            for (int r = 0; r < 4; ++r) {
                float ssq = 0.f;
                #pragma unroll
                for (int n = 0; n < 4; ++n) { float vv = aacc[mt2][n][r]; ssq += vv * vv; }
                ssq += __shfl_xor(ssq, 1, 64);
                ssq += __shfl_xor(ssq, 2, 64);
                ssq += __shfl_xor(ssq, 4, 64);
                ssq += __shfl_xor(ssq, 8, 64);
                if (n15 == 0) red_s[(mt2 * 16 + q * 4 + r) * 4 + w] = ssq;
            }
        __syncthreads();   // sync3: red_s complete
        #pragma unroll
        for (int mt2 = 0; mt2 < 2; ++mt2)
            #pragma unroll
            for (int r = 0; r < 4; ++r) {
                const int row = mt2 * 16 + q * 4 + r;
                const float s = red_s[row * 4] + red_s[row * 4 + 1]
                              + red_s[row * 4 + 2] + red_s[row * 4 + 3];
                const float inr = 1.f / fmaxf(sqrtf(s), 1e-12f);
                #pragma unroll
                for (int n = 0; n < 4; ++n) sa_acc[n] += aacc[mt2][n][r] * inr;
            }
        // next chunk's Xa/XaT writes are safe: all attend reads preceded sync3
    }

    // ---- ap row norms + rank-1 contraction ----
    __syncthreads();   // protect red_s from last invn reads
    #pragma unroll
    for (int mt2 = 0; mt2 < 2; ++mt2)
        #pragma unroll
        for (int r = 0; r < 4; ++r) {
            float ssq = 0.f;
            #pragma unroll
            for (int n = 0; n < 4; ++n) { float vv = apacc[mt2][n][r]; ssq += vv * vv; }
            ssq += __shfl_xor(ssq, 1, 64);
            ssq += __shfl_xor(ssq, 2, 64);
            ssq += __shfl_xor(ssq, 4, 64);
            ssq += __shfl_xor(ssq, 8, 64);
            if (n15 == 0) red_s[(mt2 * 16 + q * 4 + r) * 4 + w] = ssq;
        }
    __syncthreads();

    float inr_ap[2][4];
    #pragma unroll
    for (int mt2 = 0; mt2 < 2; ++mt2)
        #pragma unroll
        for (int r = 0; r < 4; ++r) {
            const int row = mt2 * 16 + q * 4 + r;
            const float s = red_s[row * 4] + red_s[row * 4 + 1]
                          + red_s[row * 4 + 2] + red_s[row * 4 + 3];
            inr_ap[mt2][r] = 1.f / fmaxf(sqrtf(s), 1e-12f);
        }

    float prod = 0.f;
    #pragma unroll
    for (int n = 0; n < 4; ++n) {
        float sp = 0.f;
        #pragma unroll
        for (int mt2 = 0; mt2 < 2; ++mt2)
            #pragma unroll
            for (int r = 0; r < 4; ++r)
                sp += apacc[mt2][n][r] * inr_ap[mt2][r];
        float saf = sa_acc[n];
        saf += __shfl_xor(saf, 16, 64);
        saf += __shfl_xor(saf, 32, 64);
        float spf = sp;
        spf += __shfl_xor(spf, 16, 64);
        spf += __shfl_xor(spf, 32, 64);
        prod += saf * spf;
    }
    prod += __shfl_xor(prod, 1, 64);
    prod += __shfl_xor(prod, 2, 64);
    prod += __shfl_xor(prod, 4, 64);
    prod += __shfl_xor(prod, 8, 64);
    prod += __shfl_xor(prod, 16, 64);
    prod += __shfl_xor(prod, 32, 64);
    if (l == 0) wred_s[w] = prod;
    __syncthreads();
    if (tid == 0)
        out_sim[t * NB + v] = (wred_s[0] + wred_s[1] + wred_s[2] + wred_s[3]) * 0.25f
                              / ((float)Av * 30.f);
}

// ---------------------------------------------------------------------------
extern "C" void kernel_launch(void* const* d_in, const int* in_sizes, int n_in,
                              void* d_out, int out_size, void* d_ws, size_t ws_size,
                              hipStream_t stream)
{
    const float* vf = (const float*)d_in[0];
    const float* tf = (const float*)d_in[1];
    const int*   an = (const int*)d_in[3];
    const float* Wv = (const float*)d_in[4];
    const float* bv = (const float*)d_in[5];
    const float* Wt = (const float*)d_in[6];
    const float* bt = (const float*)d_in[7];
    const float* Wp = (const float*)d_in[8];
    const float* bp = (const float*)d_in[9];
    const float* Wa = (const float*)d_in[10];
    const float* ba = (const float*)d_in[11];

    float* out = (float*)d_out;
    float* out_vis = out;
    float* out_txt = out + 8192;
    float* out_pm  = out + 16384;
    float* out_am  = out + 24576;
    float* out_sim = out + 32768;

    // ws: Apack 11,108,352 B | Bpack 1,572,864 B | frags 7,340,032 B = 20.0 MB
    __bf16* Apack = (__bf16*)d_ws;                       // A_SLOTS*8 elems
    __bf16* Bpack = Apack + (size_t)A_SLOTS * 8;
    __bf16* frag0 = Bpack + (size_t)B_SLOTS * 8;
    __bf16* pn_frag   = frag0;                           // 1,572,864 elems
    __bf16* pB_frag   = frag0 + 1572864;                 // 1,572,864
    __bf16* an_frag   = frag0 + 3145728;                 // 262,144
    __bf16* attT_frag = frag0 + 3407872;                 // 262,144

    prepack_kernel<<<(A_SLOTS + B_SLOTS) / 256, 256, 0, stream>>>(
        vf, tf, Wp, Wa, Wv, Wt, Apack, Bpack, out + 16384);

    gemm_pack_kernel<<<452, 256, 0, stream>>>(
        Apack, Bpack, bv, bt, bp, ba, an,
        out_vis, out_txt, out_pm, out_am,
        pn_frag, pB_frag, an_frag, attT_frag);

    pair_mfma_kernel<<<dim3(NB, NB), 256, 0, stream>>>(
        pn_frag, pB_frag, an_frag, attT_frag, an, out_sim);
}